// Round 2
// baseline (187.767 us; speedup 1.0000x reference)
//
#include <hip/hip_runtime.h>

// ---------------------------------------------------------------------------
// DeltaThetaGammaCLEVRN — f32 I/O (reference dtype; confirmed via the 2%-of-
// max|ref| threshold arithmetic in round 1).
//
// The oscillator phases are dead code w.r.t. the output: the amplitude ODE
// da = a(1-a^2) never reads phases, and ad0=at0=1 is an exact fixed point.
// Effective per-sample computation:
//   sf[16]  = mean_n scene[b,n,:]
//   g[64]   = sigmoid(sf @ Ws + bs); 20x: g += 0.01*(g - g^3)
//   h[64]   = relu(b_eff + g @ W1g + query[b] @ Wq_fold)
//   logits  = h @ W2 + b2;  out = log_softmax(logits)
// Wq_fold = query_w @ ro_w1[88:152]  (query path is linear -> foldable)
// b_eff   = ro_b1 + colsum(ro_w1[0:24]) + query_b @ ro_w1[88:152]
// Inputs d_in[2..7] (phases/freqs) are never read (~23 MB saved).
// ---------------------------------------------------------------------------

// f32 workspace layout (element offsets)
#define WS_WQ    0      // Wq_fold [60][64]
#define WS_BEFF  3840   // b_eff   [64]
// total 3904 f32 = 15,616 bytes

__global__ __launch_bounds__(64) void dtg_prep(
    const float* __restrict__ qw, const float* __restrict__ qb,
    const float* __restrict__ w1, const float* __restrict__ b1,
    float* __restrict__ ws)
{
  const int blk = blockIdx.x, c = threadIdx.x;
  if (blk < 60) {                 // Wq_fold row k = blk, column c
    float acc = 0.f;
    for (int j = 0; j < 64; ++j)
      acc = fmaf(qw[blk * 64 + j], w1[(88 + j) * 64 + c], acc);
    ws[WS_WQ + blk * 64 + c] = acc;
  } else {                        // b_eff
    float acc = b1[c];
    for (int r = 0; r < 24; ++r) acc += w1[r * 64 + c];
    for (int j = 0; j < 64; ++j)
      acc = fmaf(qb[j], w1[(88 + j) * 64 + c], acc);
    ws[WS_BEFF + c] = acc;
  }
}

// 4 k-rows x 64 cols FMA body; weight rows have lane-uniform addresses so the
// compiler can keep them in scalar loads / L1-broadcast.
#define MV4(ACC, X0, X1, X2, X3, R0, R1, R2, R3)                                   \
  { _Pragma("unroll")                                                              \
    for (int c = 0; c < 16; ++c) {                                                 \
      float4 wa = (R0)[c], wb = (R1)[c], wc = (R2)[c], wd = (R3)[c];               \
      ACC[4*c+0] = fmaf(X0,wa.x, fmaf(X1,wb.x, fmaf(X2,wc.x, fmaf(X3,wd.x, ACC[4*c+0])))); \
      ACC[4*c+1] = fmaf(X0,wa.y, fmaf(X1,wb.y, fmaf(X2,wc.y, fmaf(X3,wd.y, ACC[4*c+1])))); \
      ACC[4*c+2] = fmaf(X0,wa.z, fmaf(X1,wb.z, fmaf(X2,wc.z, fmaf(X3,wd.z, ACC[4*c+2])))); \
      ACC[4*c+3] = fmaf(X0,wa.w, fmaf(X1,wb.w, fmaf(X2,wc.w, fmaf(X3,wd.w, ACC[4*c+3])))); \
    } }

__global__ __launch_bounds__(128) void dtg_main(
    const float* __restrict__ scene,
    const float* __restrict__ query,
    const float* __restrict__ sw,    // scene_w [16][64]
    const float* __restrict__ sb,    // scene_b [64]
    const float* __restrict__ w1,    // ro_w1 [152][64]; rows 24..87 used here
    const float* __restrict__ w2,    // ro_w2 [64][2]
    const float* __restrict__ b2,    // ro_b2 [2]
    const float* __restrict__ ws,    // prep results
    float2* __restrict__ out,
    int B)
{
  // per-thread LDS slot, stride 65 f32: consecutive lanes land on consecutive
  // banks (65 % 32 == 1), so lane-parallel slot access is conflict-free.
  __shared__ float stage[128 * 65];
  const int tid = threadIdx.x;
  const int b = blockIdx.x * 128 + tid;
  if (b >= B) return;
  float* slot = &stage[tid * 65];

  const float* Wq   = ws + WS_WQ;
  const float* beff = ws + WS_BEFF;
  const float* W1g  = w1 + 24 * 64;   // rows 24..87, contiguous

  // ---- scene_flat = mean over 8 rows of 16 (128 consecutive f32 per sample)
  const float4* sp = (const float4*)(scene + (size_t)b * 128);
  float sf[16];
#pragma unroll
  for (int k = 0; k < 16; ++k) sf[k] = 0.f;
#pragma unroll
  for (int n = 0; n < 8; ++n) {
#pragma unroll
    for (int q = 0; q < 4; ++q) {
      float4 v = sp[4 * n + q];
      sf[4*q+0] += v.x; sf[4*q+1] += v.y; sf[4*q+2] += v.z; sf[4*q+3] += v.w;
    }
  }
#pragma unroll
  for (int k = 0; k < 16; ++k) slot[k] = sf[k] * 0.125f;

  // ---- g = sf @ Ws + bs  (x streamed from LDS so the k-loop stays rolled)
  float g[64];
#pragma unroll
  for (int c = 0; c < 16; ++c) {
    float4 v = ((const float4*)sb)[c];
    g[4*c+0] = v.x; g[4*c+1] = v.y; g[4*c+2] = v.z; g[4*c+3] = v.w;
  }
  for (int kc = 0; kc < 4; ++kc) {
    float x0 = slot[4*kc+0], x1 = slot[4*kc+1], x2 = slot[4*kc+2], x3 = slot[4*kc+3];
    const float4* r0 = (const float4*)(sw + (4*kc+0)*64);
    const float4* r1 = (const float4*)(sw + (4*kc+1)*64);
    const float4* r2 = (const float4*)(sw + (4*kc+2)*64);
    const float4* r3 = (const float4*)(sw + (4*kc+3)*64);
    MV4(g, x0, x1, x2, x3, r0, r1, r2, r3)
  }

  // ---- sigmoid + 20 Euler steps of g += 0.01*(g - g^3)
#pragma unroll
  for (int c = 0; c < 64; ++c)
    g[c] = __builtin_amdgcn_rcpf(1.f + __expf(-g[c]));
  for (int t = 0; t < 20; ++t) {
#pragma unroll
    for (int c = 0; c < 64; ++c) {
      float a = g[c];
      g[c] = fmaf(0.01f, a - a * a * a, a);
    }
  }
#pragma unroll
  for (int c = 0; c < 64; ++c) slot[c] = g[c];   // stage g, free the regs

  // ---- h = b_eff + query @ Wq_fold + g @ W1g
  float h[64];
#pragma unroll
  for (int c = 0; c < 16; ++c) {
    float4 v = ((const float4*)beff)[c];
    h[4*c+0] = v.x; h[4*c+1] = v.y; h[4*c+2] = v.z; h[4*c+3] = v.w;
  }
  const float4* qp = (const float4*)(query + (size_t)b * 60);  // 240 B, 16-aligned
  for (int kc = 0; kc < 15; ++kc) {
    float4 qv = qp[kc];
    const float4* r0 = (const float4*)(Wq + (4*kc+0)*64);
    const float4* r1 = (const float4*)(Wq + (4*kc+1)*64);
    const float4* r2 = (const float4*)(Wq + (4*kc+2)*64);
    const float4* r3 = (const float4*)(Wq + (4*kc+3)*64);
    MV4(h, qv.x, qv.y, qv.z, qv.w, r0, r1, r2, r3)
  }
  for (int kc = 0; kc < 16; ++kc) {
    float x0 = slot[4*kc+0], x1 = slot[4*kc+1], x2 = slot[4*kc+2], x3 = slot[4*kc+3];
    const float4* r0 = (const float4*)(W1g + (4*kc+0)*64);
    const float4* r1 = (const float4*)(W1g + (4*kc+1)*64);
    const float4* r2 = (const float4*)(W1g + (4*kc+2)*64);
    const float4* r3 = (const float4*)(W1g + (4*kc+3)*64);
    MV4(h, x0, x1, x2, x3, r0, r1, r2, r3)
  }

  // ---- logits + log_softmax(2)
  float l0 = b2[0], l1 = b2[1];
#pragma unroll
  for (int c = 0; c < 64; ++c) {
    float r = fmaxf(h[c], 0.f);
    float2 w = ((const float2*)w2)[c];
    l0 = fmaf(r, w.x, l0);
    l1 = fmaf(r, w.y, l1);
  }
  float m   = fmaxf(l0, l1);
  float e0  = __expf(l0 - m), e1 = __expf(l1 - m);
  float lse = m + __logf(e0 + e1);
  out[b] = make_float2(l0 - lse, l1 - lse);
}

extern "C" void kernel_launch(void* const* d_in, const int* in_sizes, int n_in,
                              void* d_out, int out_size, void* d_ws, size_t ws_size,
                              hipStream_t stream)
{
  const float* scene = (const float*)d_in[0];
  const float* query = (const float*)d_in[1];
  // d_in[2..7] = phases/freqs: dead code w.r.t. the output, never read
  const float* sw = (const float*)d_in[8];
  const float* sb = (const float*)d_in[9];
  const float* qw = (const float*)d_in[10];
  const float* qb = (const float*)d_in[11];
  const float* w1 = (const float*)d_in[12];
  const float* b1 = (const float*)d_in[13];
  const float* w2 = (const float*)d_in[14];
  const float* b2 = (const float*)d_in[15];
  float* ws = (float*)d_ws;
  const int B = in_sizes[0] / 128;   // 65536

  hipLaunchKernelGGL(dtg_prep, dim3(61), dim3(64), 0, stream,
                     qw, qb, w1, b1, ws);
  hipLaunchKernelGGL(dtg_main, dim3((B + 127) / 128), dim3(128), 0, stream,
                     scene, query, sw, sb, w1, w2, b2, ws, (float2*)d_out, B);
}

// Round 3
// 149.582 us; speedup vs baseline: 1.2553x; 1.2553x over previous
//
#include <hip/hip_runtime.h>

// ---------------------------------------------------------------------------
// DeltaThetaGammaCLEVRN — f32 I/O. Oscillator phases are dead code (amplitude
// ODE is phase-independent, ad0=at0=1 is a fixed point). Per sample:
//   sf[16] = mean_n scene;  g = sigmoid(sf@Ws+bs);  20x: g += .01*(g-g^3)
//   h = relu(beff + [query|g] @ W12);  logits = h@W2+b2; log_softmax.
// Round-3 structure: 16 lanes per sample (4x4 register tile per thread),
// all k-loop operands from LDS, 4096 waves (vs 1024 in round 2).
// ---------------------------------------------------------------------------

// global workspace layout (f32 offsets), filled by dtg_prep
#define WS_W12  0      // [124][64]: rows 0..59 = Wq_fold, 60..123 = ro_w1[24:88]
#define WS_WS   7936   // [16][64]  scene_w
#define WS_BS   8960   // [64]      scene_b
#define WS_BEFF 9024   // [64]      folded bias
#define WS_W2   9088   // [64][2]
#define WS_B2   9216   // [2]
#define WS_TOT  9218

__global__ __launch_bounds__(256) void dtg_prep(
    const float* __restrict__ sw, const float* __restrict__ sb,
    const float* __restrict__ qw, const float* __restrict__ qb,
    const float* __restrict__ w1, const float* __restrict__ b1,
    const float* __restrict__ w2, const float* __restrict__ b2,
    float* __restrict__ ws)
{
  __shared__ float sm[256];
  const int blk = blockIdx.x, tid = threadIdx.x;
  if (blk < 60) {
    // Wq_fold row k=blk: 64 outputs, 4 partial-threads each (K=64 split by 16)
    const int c = tid & 63, p = tid >> 6;
    float acc = 0.f;
    for (int j = p * 16; j < p * 16 + 16; ++j)
      acc = fmaf(qw[blk * 64 + j], w1[(88 + j) * 64 + c], acc);
    sm[tid] = acc;
    __syncthreads();
    if (tid < 64)
      ws[WS_W12 + blk * 64 + tid] = sm[tid] + sm[64 + tid] + sm[128 + tid] + sm[192 + tid];
  } else if (blk == 60) {
    // b_eff = b1 + colsum(w1[0:24]) + qb @ w1[88:152]
    const int c = tid & 63, p = tid >> 6;
    float acc = 0.f;
    if (p == 0) {
      acc = b1[c];
      for (int r = 0; r < 24; ++r) acc += w1[r * 64 + c];
    }
    for (int j = p * 16; j < p * 16 + 16; ++j)
      acc = fmaf(qb[j], w1[(88 + j) * 64 + c], acc);
    sm[tid] = acc;
    __syncthreads();
    if (tid < 64)
      ws[WS_BEFF + tid] = sm[tid] + sm[64 + tid] + sm[128 + tid] + sm[192 + tid];
  } else if (blk == 61) {
    // small copies: Ws, bs, W2, b2
    for (int i = tid; i < 1218; i += 256) {
      if      (i < 1024) ws[WS_WS + i]          = sw[i];
      else if (i < 1088) ws[WS_BS + (i - 1024)] = sb[i - 1024];
      else if (i < 1216) ws[WS_W2 + (i - 1088)] = w2[i - 1088];
      else               ws[WS_B2 + (i - 1216)] = b2[i - 1216];
    }
  } else {
    // W1g copy: ws[3840..7936) = w1 rows 24..87 (4096 f32, 2048 per block)
    const int base = (blk - 62) * 2048;
    for (int j = 0; j < 8; ++j) {
      int i = base + tid + 256 * j;
      ws[WS_W12 + 3840 + i] = w1[1536 + i];
    }
  }
}

// LDS layout (f32 words): weights [0..9218) mirror ws; then transposed x.
#define L_X2   9220              // [124][68]: rows 0..59 q_t, 60..123 g_t
#define L_SF   (9220 + 124*68)   // [16][68]  = 17652
#define L_TOT  (17652 + 16*68)   // 18740 words = 74,960 B -> 2 blocks/CU

__global__ __launch_bounds__(256) void dtg_main(
    const float* __restrict__ scene,
    const float* __restrict__ query,
    const float* __restrict__ ws,
    float* __restrict__ outf)
{
  __shared__ float lds[L_TOT];
  const int tid = threadIdx.x;
  const int blk = blockIdx.x;

  // ---- stage weights ws -> LDS (coalesced f4)
  {
    const float4* src = (const float4*)ws;
    float4* dst = (float4*)lds;
#pragma unroll
    for (int i = 0; i < 9; ++i) {
      int idx = tid + 256 * i;
      dst[idx] = src[idx];
    }
    if (tid < 2) lds[9216 + tid] = ws[9216 + tid];
  }

  // ---- stage scene -> sf_t[k][68] and query -> q_t rows of X2
  {
    const int s = tid >> 2, q = tid & 3;           // sample-in-block, quad
    const float4* sp = (const float4*)scene + (size_t)blk * 2048;
    float4 a = make_float4(0.f, 0.f, 0.f, 0.f);
#pragma unroll
    for (int n = 0; n < 8; ++n) {
      float4 v = sp[s * 32 + n * 4 + q];
      a.x += v.x; a.y += v.y; a.z += v.z; a.w += v.w;
    }
    lds[L_SF + (4 * q + 0) * 68 + s] = a.x * 0.125f;
    lds[L_SF + (4 * q + 1) * 68 + s] = a.y * 0.125f;
    lds[L_SF + (4 * q + 2) * 68 + s] = a.z * 0.125f;
    lds[L_SF + (4 * q + 3) * 68 + s] = a.w * 0.125f;

    const float4* qp = (const float4*)query + (size_t)blk * 960;  // 64*15 f4
#pragma unroll
    for (int m = 0; m < 4; ++m) {
      int f4i = q + 4 * m;
      if (f4i < 15) {
        float4 v = qp[s * 15 + f4i];
        int k0 = 4 * f4i;
        lds[L_X2 + (k0 + 0) * 68 + s] = v.x;
        lds[L_X2 + (k0 + 1) * 68 + s] = v.y;
        lds[L_X2 + (k0 + 2) * 68 + s] = v.z;
        lds[L_X2 + (k0 + 3) * 68 + s] = v.w;
      }
    }
  }
  __syncthreads();

  // ---- thread = (sgrp: 4 samples) x (cgrp: 4 cols)
  const int sgrp = tid >> 4, cgrp = tid & 15;
  const float* Ws   = lds + WS_WS;
  const float* W12  = lds + WS_W12;

  // stage 1: g[4s][4c] = bs + sf @ Ws
  float ga[4][4];
  {
    float4 bsv = *(const float4*)(lds + WS_BS + 4 * cgrp);
#pragma unroll
    for (int si = 0; si < 4; ++si) {
      ga[si][0] = bsv.x; ga[si][1] = bsv.y; ga[si][2] = bsv.z; ga[si][3] = bsv.w;
    }
#pragma unroll
    for (int k = 0; k < 16; ++k) {
      float4 xv = *(const float4*)(lds + L_SF + k * 68 + 4 * sgrp);
      float4 wv = *(const float4*)(Ws + k * 64 + 4 * cgrp);
      const float x[4] = {xv.x, xv.y, xv.z, xv.w};
      const float w[4] = {wv.x, wv.y, wv.z, wv.w};
#pragma unroll
      for (int si = 0; si < 4; ++si)
#pragma unroll
        for (int ci = 0; ci < 4; ++ci)
          ga[si][ci] = fmaf(x[si], w[ci], ga[si][ci]);
    }
  }

  // sigmoid + 20 Euler steps
#pragma unroll
  for (int si = 0; si < 4; ++si)
#pragma unroll
    for (int ci = 0; ci < 4; ++ci)
      ga[si][ci] = __builtin_amdgcn_rcpf(1.f + __expf(-ga[si][ci]));
  for (int t = 0; t < 20; ++t) {
#pragma unroll
    for (int si = 0; si < 4; ++si)
#pragma unroll
      for (int ci = 0; ci < 4; ++ci) {
        float a = ga[si][ci];
        ga[si][ci] = fmaf(0.01f, a - a * a * a, a);
      }
  }

  // g -> X2 rows 60+c (transposed, 4 samples contiguous per write)
#pragma unroll
  for (int ci = 0; ci < 4; ++ci) {
    float4 gw = make_float4(ga[0][ci], ga[1][ci], ga[2][ci], ga[3][ci]);
    *(float4*)(lds + L_X2 + (60 + 4 * cgrp + ci) * 68 + 4 * sgrp) = gw;
  }
  __syncthreads();

  // stage 2: h = beff + [q|g] @ W12   (K = 124)
  float ha[4][4];
  {
    float4 bev = *(const float4*)(lds + WS_BEFF + 4 * cgrp);
#pragma unroll
    for (int si = 0; si < 4; ++si) {
      ha[si][0] = bev.x; ha[si][1] = bev.y; ha[si][2] = bev.z; ha[si][3] = bev.w;
    }
#pragma unroll 4
    for (int k = 0; k < 124; ++k) {
      float4 xv = *(const float4*)(lds + L_X2 + k * 68 + 4 * sgrp);
      float4 wv = *(const float4*)(W12 + k * 64 + 4 * cgrp);
      const float x[4] = {xv.x, xv.y, xv.z, xv.w};
      const float w[4] = {wv.x, wv.y, wv.z, wv.w};
#pragma unroll
      for (int si = 0; si < 4; ++si)
#pragma unroll
        for (int ci = 0; ci < 4; ++ci)
          ha[si][ci] = fmaf(x[si], w[ci], ha[si][ci]);
    }
  }

  // logits: relu + W2, reduce over the 16 col-lanes (lane bits 0..3)
  float l0[4], l1[4];
  {
    float2 w2c[4];
#pragma unroll
    for (int ci = 0; ci < 4; ++ci)
      w2c[ci] = *(const float2*)(lds + WS_W2 + (4 * cgrp + ci) * 2);
#pragma unroll
    for (int si = 0; si < 4; ++si) {
      float a0 = 0.f, a1 = 0.f;
#pragma unroll
      for (int ci = 0; ci < 4; ++ci) {
        float r = fmaxf(ha[si][ci], 0.f);
        a0 = fmaf(r, w2c[ci].x, a0);
        a1 = fmaf(r, w2c[ci].y, a1);
      }
      l0[si] = a0; l1[si] = a1;
    }
  }
#pragma unroll
  for (int m = 1; m < 16; m <<= 1) {
#pragma unroll
    for (int si = 0; si < 4; ++si) {
      l0[si] += __shfl_xor(l0[si], m);
      l1[si] += __shfl_xor(l1[si], m);
    }
  }
  if (cgrp == 0) {
    const float bb0 = lds[WS_B2 + 0], bb1 = lds[WS_B2 + 1];
    const int base = blk * 64 + 4 * sgrp;
    float r[8];
#pragma unroll
    for (int si = 0; si < 4; ++si) {
      float a0 = l0[si] + bb0, a1 = l1[si] + bb1;
      float mx  = fmaxf(a0, a1);
      float e0  = __expf(a0 - mx), e1 = __expf(a1 - mx);
      float lse = mx + __logf(e0 + e1);
      r[2 * si] = a0 - lse; r[2 * si + 1] = a1 - lse;
    }
    float4* op = (float4*)(outf + 2 * base);
    op[0] = make_float4(r[0], r[1], r[2], r[3]);
    op[1] = make_float4(r[4], r[5], r[6], r[7]);
  }
}

extern "C" void kernel_launch(void* const* d_in, const int* in_sizes, int n_in,
                              void* d_out, int out_size, void* d_ws, size_t ws_size,
                              hipStream_t stream)
{
  const float* scene = (const float*)d_in[0];
  const float* query = (const float*)d_in[1];
  // d_in[2..7] = phases/freqs: dead code w.r.t. the output, never read
  const float* sw = (const float*)d_in[8];
  const float* sb = (const float*)d_in[9];
  const float* qw = (const float*)d_in[10];
  const float* qb = (const float*)d_in[11];
  const float* w1 = (const float*)d_in[12];
  const float* b1 = (const float*)d_in[13];
  const float* w2 = (const float*)d_in[14];
  const float* b2 = (const float*)d_in[15];
  float* ws = (float*)d_ws;
  const int B = in_sizes[0] / 128;   // 65536

  hipLaunchKernelGGL(dtg_prep, dim3(64), dim3(256), 0, stream,
                     sw, sb, qw, qb, w1, b1, w2, b2, ws);
  hipLaunchKernelGGL(dtg_main, dim3(B / 64), dim3(256), 0, stream,
                     scene, query, ws, (float*)d_out);
}